// Round 9
// baseline (323.578 us; speedup 1.0000x reference)
//
#include <hip/hip_runtime.h>
#include <math.h>

namespace {

constexpr int H = 2048;
constexpr int W = 2048;
constexpr int HW = H * W;
constexpr int TR = 8;                 // tile rows
constexpr int TC = 512;               // tile cols
constexpr int NTX = W / TC;           // 4 tile cols
constexpr int NTY = H / TR;           // 256 tile rows
constexpr int BPY = NTY / 8;          // 32 row-tiles per XCD band

constexpr float TANH_C  = 1.1486328125f;
constexpr float DEG2RAD = 0.017453292519943295f; // np.float32(pi/180)
constexpr float RT2H    = 0.70710678118654752f;  // sqrt(2)/2
constexpr float LOG2E   = 1.4426950408889634f;   // log2(e)
constexpr float TWOPI   = 6.283185307179586f;

// --- guarded HW-transcendental wrappers (single VALU op each) ---
__device__ __forceinline__ float fexp2(float x) {
#if __has_builtin(__builtin_amdgcn_exp2f)
    return __builtin_amdgcn_exp2f(x);          // v_exp_f32: 2^x
#else
    return __exp2f(x);
#endif
}
__device__ __forceinline__ float fcos_rev(float x) {  // cos(2*pi*x)
#if __has_builtin(__builtin_amdgcn_cosf)
    return __builtin_amdgcn_cosf(x);           // v_cos_f32: revolutions
#else
    return __cosf(x * TWOPI);
#endif
}
__device__ __forceinline__ float fsin_rev(float x) {  // sin(2*pi*x)
#if __has_builtin(__builtin_amdgcn_sinf)
    return __builtin_amdgcn_sinf(x);
#else
    return __sinf(x * TWOPI);
#endif
}
__device__ __forceinline__ float frcp(float x) {
#if __has_builtin(__builtin_amdgcn_rcpf)
    return __builtin_amdgcn_rcpf(x);           // v_rcp_f32
#else
    return 1.0f / x;
#endif
}

// out layout: [0,HW) p_ignite, [HW,2HW) new_burning (0/1), [2HW,3HW) new_burned
// Block = 256 threads owns an 8x512 tile (16 cells/thread in 4 groups of 4).
// KEY CHANGE vs R8: all dense per-cell streams (6 float fields + burned) are
// issued SPECULATIVELY AT KERNEL ENTRY (28 vector loads/thread, held in
// registers) so their ~900cy cold-HBM latency overlaps the burning staging +
// barrier + detection instead of serializing after it. After the barrier the
// only memory traffic is the scattered slope gather (gated, irreducible) and
// the dense output stores. No worklist, one barrier.
__global__ __launch_bounds__(256) void wildfire_step(
    const float* __restrict__ p_veg,  const float* __restrict__ p_den,
    const float* __restrict__ wind_v, const float* __restrict__ wind_d,
    const float* __restrict__ slope,
    const float* __restrict__ s_a,  const float* __restrict__ s_ph,
    const float* __restrict__ s_c1, const float* __restrict__ s_c2,
    const float* __restrict__ s_pc,
    const float* __restrict__ rand_ig, const float* __restrict__ rand_co,
    const int* __restrict__ burning, const int* __restrict__ burned,
    float* __restrict__ out)
{
    // sb[r][4+c] = burning(i0-1+r, j0+c), c in [0,512); [3]/[516] = col halo
    __shared__ __align__(16) float sb[TR + 2][520];   // 20.8 KB

    const int t  = (int)threadIdx.x;
    const int g  = (int)blockIdx.y;
    const int ty = (g & 7) * BPY + (g >> 3);   // bijective XCD band decode
    const int tx = (int)blockIdx.x;
    const int i0 = ty * TR;
    const int j0 = tx * TC;

    // ---- Entry: speculative dense prefetch of all owned-cell streams ----
    float4 pv4[4], pd4[4], wv4[4], wd4[4], rg4[4], rc4[4];
    int4   bd4[4];
    int    gix[4];
#pragma unroll
    for (int k = 0; k < 4; ++k) {
        const int p   = t + (k << 8);           // [0,1024)
        const int row = p >> 7;                 // 0..7
        const int jb  = (p & 127) * 4;          // 0..508
        const int gi  = (i0 + row) * W + j0 + jb;   // 16B-aligned
        gix[k] = gi;
        pv4[k] = *reinterpret_cast<const float4*>(p_veg  + gi);
        pd4[k] = *reinterpret_cast<const float4*>(p_den  + gi);
        wv4[k] = *reinterpret_cast<const float4*>(wind_v + gi);
        wd4[k] = *reinterpret_cast<const float4*>(wind_d + gi);
        rg4[k] = *reinterpret_cast<const float4*>(rand_ig + gi);
        rc4[k] = *reinterpret_cast<const float4*>(rand_co + gi);
        bd4[k] = *reinterpret_cast<const int4*>(burned + gi);
    }

    // ---- Phase A: stage burning halo (overlaps the prefetch above) ----
    for (int p = t; p < (TR + 2) * (TC / 4); p += 256) {
        const int r  = p >> 7;                  // / 128
        const int gq = p & 127;
        const int ii = i0 - 1 + r;
        int4 v = make_int4(0, 0, 0, 0);
        if (ii >= 0 && ii < H)
            v = *reinterpret_cast<const int4*>(burning + ii * W + j0 + 4 * gq);
        float4 f;
        f.x = v.x ? 1.f : 0.f;  f.y = v.y ? 1.f : 0.f;
        f.z = v.z ? 1.f : 0.f;  f.w = v.w ? 1.f : 0.f;
        *reinterpret_cast<float4*>(&sb[r][4 + 4 * gq]) = f;   // aligned
    }
    if (t < TR + 2) {                                   // left col halo
        const int ii = i0 - 1 + t;
        sb[t][3] = (ii >= 0 && ii < H && j0 > 0)
                 ? (burning[ii * W + j0 - 1] ? 1.f : 0.f) : 0.f;
    } else if (t >= 64 && t < 64 + TR + 2) {            // right col halo
        const int r  = t - 64;
        const int ii = i0 - 1 + r;
        sb[r][4 + TC] = (ii >= 0 && ii < H && j0 + TC < W)
                 ? (burning[ii * W + j0 + TC] ? 1.f : 0.f) : 0.f;
    }
    __syncthreads();

    // ---- Compute + store, all register-fed except gated slope gather ----
    const float a_   = s_a[0];
    const float p_h  = s_ph[0];
    const float c1   = s_c1[0];
    const float c2   = s_c2[0];
    const float p_cont = s_pc[0];
    const float aslL = (a_ * DEG2RAD) * LOG2E;
    const float CzK  = 2.f * LOG2E * TANH_C;

#pragma unroll
    for (int k = 0; k < 4; ++k) {
        const int p   = t + (k << 8);
        const int row = p >> 7;
        const int jb  = (p & 127) * 4;
        const float4 av = *reinterpret_cast<const float4*>(&sb[row][4 + jb]);
        const float4 bv = *reinterpret_cast<const float4*>(&sb[row + 1][4 + jb]);
        const float4 cv = *reinterpret_cast<const float4*>(&sb[row + 2][4 + jb]);
        const float r0[6] = {sb[row][3 + jb],     av.x, av.y, av.z, av.w, sb[row][8 + jb]};
        const float r1[6] = {sb[row + 1][3 + jb], bv.x, bv.y, bv.z, bv.w, sb[row + 1][8 + jb]};
        const float r2[6] = {sb[row + 2][3 + jb], cv.x, cv.y, cv.z, cv.w, sb[row + 2][8 + jb]};

        const float pv[4]  = {pv4[k].x, pv4[k].y, pv4[k].z, pv4[k].w};
        const float pd[4]  = {pd4[k].x, pd4[k].y, pd4[k].z, pd4[k].w};
        const float wv[4]  = {wv4[k].x, wv4[k].y, wv4[k].z, wv4[k].w};
        const float wd[4]  = {wd4[k].x, wd4[k].y, wd4[k].z, wd4[k].w};
        const float rg[4]  = {rg4[k].x, rg4[k].y, rg4[k].z, rg4[k].w};
        const float rc[4]  = {rc4[k].x, rc4[k].y, rc4[k].z, rc4[k].w};
        const int   bn[4]  = {bd4[k].x, bd4[k].y, bd4[k].z, bd4[k].w};

        float4 o0, o1, o2;
        float* o0p = &o0.x; float* o1p = &o1.x; float* o2p = &o2.x;
#pragma unroll
        for (int x = 0; x < 4; ++x) {
            const float anyn = ((r0[x] + r0[x+1]) + (r0[x+2] + r1[x]))
                             + ((r1[x+2] + r2[x]) + (r2[x+1] + r2[x+2]));
            const bool isb = (r1[x+1] != 0.f);
            float pig = 0.f;
            bool  ni  = false;

            if (anyn != 0.f) {                  // exec-masked heavy path
                const int gidx = gix[k] + x;
                float sl[9];                    // the only post-barrier load
                __builtin_memcpy(sl, slope + (size_t)gidx * 9, 9 * sizeof(float));

                const float wrev = wd[x] * (1.f / 360.f);   // revolutions
                const float cw = fcos_rev(wrev);
                const float sw = fsin_rev(wrev);

                const float Lc2wv = (LOG2E * c2) * wv[x];
                const float cwv = Lc2wv * cw, swv = Lc2wv * sw;
                const float cwr = RT2H * cwv, swr = RT2H * swv;
                const float dpl = cwr + swr;   //  45 deg
                const float dmi = cwr - swr;   // 315 deg
                const float p_base = (p_h * (1.f + pv[x])) * (1.f + pd[x]);
                const float Cz2 = CzK * p_base
                                * fexp2(LOG2E * (c1 * wv[x] - c2 * wv[x]));

#define NEIGHBOR(K, b, T, sv)                                            \
                const float q##K = fmaf(aslL, (sv), (T));                \
                const float z##K = Cz2 * fexp2(q##K);                    \
                const float E##K = fexp2(z##K);                          \
                const float d##K = fmaf((b), E##K, 1.f);

                NEIGHBOR(0, r0[x],    dmi, sl[0])   // 315
                NEIGHBOR(1, r0[x+1], -swv, sl[1])   // 270
                NEIGHBOR(2, r0[x+2], -dpl, sl[2])   // 225
                NEIGHBOR(3, r1[x],    cwv, sl[3])   //   0
                NEIGHBOR(5, r1[x+2], -cwv, sl[5])   // 180
                NEIGHBOR(6, r2[x],    dpl, sl[6])   //  45
                NEIGHBOR(7, r2[x+1],  swv, sl[7])   //  90
                NEIGHBOR(8, r2[x+2], -dmi, sl[8])   // 135
#undef NEIGHBOR
                const float den = ((d0 * d1) * (d2 * d3)) * ((d5 * d6) * (d7 * d8));
                const float num = fexp2(anyn);       // 2^(#burning nbrs), exact
                pig = fmaf(-num, frcp(den), 1.f);

                ni = (!isb) && (bn[x] == 0) && (rg[x] < pig);
            }

            const bool keep = isb && (rc[x] < p_cont);
            const bool nb   = ni || keep;
            const bool nd   = (bn[x] != 0) || (isb && !keep);
            o0p[x] = pig;
            o1p[x] = nb ? 1.f : 0.f;
            o2p[x] = nd ? 1.f : 0.f;
        }

        *reinterpret_cast<float4*>(out + gix[k])          = o0;
        *reinterpret_cast<float4*>(out + HW + gix[k])     = o1;
        *reinterpret_cast<float4*>(out + 2 * HW + gix[k]) = o2;
    }
}

} // namespace

extern "C" void kernel_launch(void* const* d_in, const int* in_sizes, int n_in,
                              void* d_out, int out_size, void* d_ws, size_t ws_size,
                              hipStream_t stream)
{
    (void)in_sizes; (void)n_in; (void)out_size; (void)d_ws; (void)ws_size;
    dim3 grid(NTX, NTY, 1);
    dim3 block(256, 1, 1);
    hipLaunchKernelGGL(wildfire_step, grid, block, 0, stream,
        (const float*)d_in[0],  (const float*)d_in[1],
        (const float*)d_in[2],  (const float*)d_in[3],
        (const float*)d_in[4],
        (const float*)d_in[5],  (const float*)d_in[6],
        (const float*)d_in[7],  (const float*)d_in[8],
        (const float*)d_in[9],
        (const float*)d_in[10], (const float*)d_in[11],
        (const int*)d_in[12],   (const int*)d_in[13],
        (float*)d_out);
}

// Round 10
// 304.513 us; speedup vs baseline: 1.0626x; 1.0626x over previous
//
#include <hip/hip_runtime.h>
#include <math.h>

namespace {

constexpr int H = 2048;
constexpr int W = 2048;
constexpr int HW = H * W;
constexpr int TRr = 4;                // tile rows
constexpr int TCc = 256;              // tile cols
constexpr int NTX = W / TCc;          // 8 tile cols
constexpr int NTY = H / TRr;          // 512 tile rows
constexpr int BPY = NTY / 8;          // 64 row-tiles per XCD band

constexpr float TANH_C  = 1.1486328125f;
constexpr float DEG2RAD = 0.017453292519943295f; // np.float32(pi/180)
constexpr float RT2H    = 0.70710678118654752f;  // sqrt(2)/2
constexpr float LOG2E   = 1.4426950408889634f;   // log2(e)
constexpr float TWOPI   = 6.283185307179586f;

// --- guarded HW-transcendental wrappers (single VALU op each) ---
__device__ __forceinline__ float fexp2(float x) {
#if __has_builtin(__builtin_amdgcn_exp2f)
    return __builtin_amdgcn_exp2f(x);          // v_exp_f32: 2^x
#else
    return __exp2f(x);
#endif
}
__device__ __forceinline__ float fcos_rev(float x) {  // cos(2*pi*x)
#if __has_builtin(__builtin_amdgcn_cosf)
    return __builtin_amdgcn_cosf(x);           // v_cos_f32: revolutions
#else
    return __cosf(x * TWOPI);
#endif
}
__device__ __forceinline__ float fsin_rev(float x) {  // sin(2*pi*x)
#if __has_builtin(__builtin_amdgcn_sinf)
    return __builtin_amdgcn_sinf(x);
#else
    return __sinf(x * TWOPI);
#endif
}
__device__ __forceinline__ float frcp(float x) {
#if __has_builtin(__builtin_amdgcn_rcpf)
    return __builtin_amdgcn_rcpf(x);           // v_rcp_f32
#else
    return 1.0f / x;
#endif
}

// out layout: [0,HW) p_ignite, [HW,2HW) new_burning (0/1), [2HW,3HW) new_burned
// Block = 256 threads owns a 4-row x 256-col tile; thread t owns the column
// j0+t (4 stacked cells). 4096 blocks -> ~8 resident blocks/CU (32 waves/CU):
// TLP is the latency-hiding mechanism (R9 showed 13% VALU / 18% BW / 25% occ
// => concurrency-starved). Loads are just-in-time and per-lane gated (the
// pattern hipcc schedules well); no cross-barrier register prefetch (R9: the
// allocator sinks it), no worklist (R3: no gain). LDS = 6.3 KB only.
__global__ __launch_bounds__(256) void wildfire_step(
    const float* __restrict__ p_veg,  const float* __restrict__ p_den,
    const float* __restrict__ wind_v, const float* __restrict__ wind_d,
    const float* __restrict__ slope,
    const float* __restrict__ s_a,  const float* __restrict__ s_ph,
    const float* __restrict__ s_c1, const float* __restrict__ s_c2,
    const float* __restrict__ s_pc,
    const float* __restrict__ rand_ig, const float* __restrict__ rand_co,
    const int* __restrict__ burning, const int* __restrict__ burned,
    float* __restrict__ out)
{
    // sb[r][4+c] = burning(i0-1+r, j0+c), c in [0,256); [3]/[260] col halo.
    // Row stride 264 floats = 1056 B (16B multiple -> aligned float4 stores).
    __shared__ __align__(16) float sb[TRr + 2][264];   // 6.3 KB

    const int t  = (int)threadIdx.x;
    const int g  = (int)blockIdx.y;
    const int ty = (g & 7) * BPY + (g >> 3);   // bijective XCD band decode
    const int i0 = ty * TRr;
    const int j0 = (int)blockIdx.x * TCc;

    // ---- stage burning halo: 6 rows x 256 cols, int4 -> float 0/1 ----
    for (int p = t; p < (TRr + 2) * (TCc / 4); p += 256) {
        const int r  = p >> 6;                  // / 64
        const int qd = p & 63;
        const int ii = i0 - 1 + r;
        int4 v = make_int4(0, 0, 0, 0);
        if (ii >= 0 && ii < H)
            v = *reinterpret_cast<const int4*>(burning + ii * W + j0 + 4 * qd);
        float4 f;
        f.x = v.x ? 1.f : 0.f;  f.y = v.y ? 1.f : 0.f;
        f.z = v.z ? 1.f : 0.f;  f.w = v.w ? 1.f : 0.f;
        *reinterpret_cast<float4*>(&sb[r][4 + 4 * qd]) = f;   // aligned
    }
    if (t < TRr + 2) {                                  // left col halo
        const int ii = i0 - 1 + t;
        sb[t][3] = (ii >= 0 && ii < H && j0 > 0)
                 ? (burning[ii * W + j0 - 1] ? 1.f : 0.f) : 0.f;
    } else if (t >= 64 && t < 64 + TRr + 2) {           // right col halo
        const int r  = t - 64;
        const int ii = i0 - 1 + r;
        sb[r][4 + TCc] = (ii >= 0 && ii < H && j0 + TCc < W)
                 ? (burning[ii * W + j0 + TCc] ? 1.f : 0.f) : 0.f;
    }
    __syncthreads();

    const float a_     = s_a[0];
    const float p_h    = s_ph[0];
    const float c1     = s_c1[0];
    const float c2     = s_c2[0];
    const float p_cont = s_pc[0];
    const float aslL   = (a_ * DEG2RAD) * LOG2E;
    const float CzK    = 2.f * LOG2E * TANH_C;

    // ---- upfront: window sums + dense burned loads (batched, static idx) --
    float anyn[TRr], bcn[TRr];
    int   bn[TRr];
#pragma unroll
    for (int x = 0; x < TRr; ++x) {
        const float b0 = sb[x][t + 3],     b1 = sb[x][t + 4],     b2 = sb[x][t + 5];
        const float b3 = sb[x + 1][t + 3], bc = sb[x + 1][t + 4], b5 = sb[x + 1][t + 5];
        const float b6 = sb[x + 2][t + 3], b7 = sb[x + 2][t + 4], b8 = sb[x + 2][t + 5];
        anyn[x] = ((b0 + b1) + (b2 + b3)) + ((b5 + b6) + (b7 + b8));
        bcn[x]  = bc;
        bn[x]   = burned[(i0 + x) * W + j0 + t];
    }

    // ---- heavy path: per-cell per-lane gated, 4 batched branch bodies ----
    float pig[TRr];
    bool  ni[TRr];
#pragma unroll
    for (int x = 0; x < TRr; ++x) {
        pig[x] = 0.f;
        ni[x]  = false;
        if (anyn[x] != 0.f) {
            const int gidx = (i0 + x) * W + j0 + t;
            const float pv  = p_veg[gidx];
            const float pd  = p_den[gidx];
            const float wv  = wind_v[gidx];
            const float wd  = wind_d[gidx];
            const float rig = rand_ig[gidx];
            float sl[9];
            __builtin_memcpy(sl, slope + (size_t)gidx * 9, 9 * sizeof(float));

            const float b0 = sb[x][t + 3],     b1 = sb[x][t + 4],     b2 = sb[x][t + 5];
            const float b3 = sb[x + 1][t + 3],                        b5 = sb[x + 1][t + 5];
            const float b6 = sb[x + 2][t + 3], b7 = sb[x + 2][t + 4], b8 = sb[x + 2][t + 5];

            const float wrev = wd * (1.f / 360.f);     // revolutions
            const float cw = fcos_rev(wrev);
            const float sw = fsin_rev(wrev);

            const float Lc2wv = (LOG2E * c2) * wv;
            const float cwv = Lc2wv * cw, swv = Lc2wv * sw;
            const float cwr = RT2H * cwv, swr = RT2H * swv;
            const float dpl = cwr + swr;   //  45 deg
            const float dmi = cwr - swr;   // 315 deg
            const float p_base = (p_h * (1.f + pv)) * (1.f + pd);
            const float Cz2 = CzK * p_base
                            * fexp2(LOG2E * (c1 * wv - c2 * wv));

#define NEIGHBOR(K, b, T, sv)                                            \
            const float q##K = fmaf(aslL, (sv), (T));                    \
            const float z##K = Cz2 * fexp2(q##K);                        \
            const float E##K = fexp2(z##K);                              \
            const float d##K = fmaf((b), E##K, 1.f);

            NEIGHBOR(0, b0,  dmi, sl[0])   // 315
            NEIGHBOR(1, b1, -swv, sl[1])   // 270
            NEIGHBOR(2, b2, -dpl, sl[2])   // 225
            NEIGHBOR(3, b3,  cwv, sl[3])   //   0
            NEIGHBOR(5, b5, -cwv, sl[5])   // 180
            NEIGHBOR(6, b6,  dpl, sl[6])   //  45
            NEIGHBOR(7, b7,  swv, sl[7])   //  90
            NEIGHBOR(8, b8, -dmi, sl[8])   // 135
#undef NEIGHBOR
            const float den = ((d0 * d1) * (d2 * d3)) * ((d5 * d6) * (d7 * d8));
            const float num = fexp2(anyn[x]);          // 2^(#burning nbrs)
            pig[x] = fmaf(-num, frcp(den), 1.f);

            ni[x] = (bcn[x] == 0.f) && (bn[x] == 0) && (rig < pig[x]);
        }
    }

    // ---- finish + stores (rand_co gated on burning, ~1% of lanes) ----
#pragma unroll
    for (int x = 0; x < TRr; ++x) {
        const int  gidx = (i0 + x) * W + j0 + t;
        const bool isb  = (bcn[x] != 0.f);
        float rcv = 1.f;
        if (isb) rcv = rand_co[gidx];
        const bool keep = isb && (rcv < p_cont);
        const bool nb   = ni[x] || keep;
        const bool nd   = (bn[x] != 0) || (isb && !keep);
        out[gidx]          = pig[x];
        out[HW + gidx]     = nb ? 1.f : 0.f;
        out[2 * HW + gidx] = nd ? 1.f : 0.f;
    }
}

} // namespace

extern "C" void kernel_launch(void* const* d_in, const int* in_sizes, int n_in,
                              void* d_out, int out_size, void* d_ws, size_t ws_size,
                              hipStream_t stream)
{
    (void)in_sizes; (void)n_in; (void)out_size; (void)d_ws; (void)ws_size;
    dim3 grid(NTX, NTY, 1);
    dim3 block(256, 1, 1);
    hipLaunchKernelGGL(wildfire_step, grid, block, 0, stream,
        (const float*)d_in[0],  (const float*)d_in[1],
        (const float*)d_in[2],  (const float*)d_in[3],
        (const float*)d_in[4],
        (const float*)d_in[5],  (const float*)d_in[6],
        (const float*)d_in[7],  (const float*)d_in[8],
        (const float*)d_in[9],
        (const float*)d_in[10], (const float*)d_in[11],
        (const int*)d_in[12],   (const int*)d_in[13],
        (float*)d_out);
}